// Round 1
// baseline (2199.258 us; speedup 1.0000x reference)
//
#include <hip/hip_runtime.h>

// DGCNN-style network, fully fused: one block per batch element (B=1024),
// 256 threads, everything resident in LDS (63.9KB, hand-packed regions).
//
// Key algebraic reductions vs reference:
//  - EdgeConv layer-1: W*[feat-center; center] = P[j] + Q[n]  (two 100x32 GEMMs)
//  - max_k leaky(z*s+t) = leaky((max_k z)*s+t)  since s>0, leaky monotone
//  - W7's g-part (512 ch, broadcast over n) folded into per-block Rg[128]

#define NPT 100
#define KK  10
#define NCH 9   // edgeconv n-chunk (E buffer = NCH*324 floats <= 3200)

struct Params {
  const float* obs;
  const float* W[10];
  const float* s[9];
  const float* t[9];
  float* out;
};

__device__ __forceinline__ float leaky(float v) { return fmaxf(v, 0.2f * v); }

// ---- kNN top-10 (stable, matches lax.top_k tie-breaking) -------------------
__device__ __forceinline__ void knn_topk(const float* __restrict__ X,
                                         float* __restrict__ xx,
                                         short* __restrict__ idx, int tid) {
  if (tid < NPT) {
    float a = 0.f;
    #pragma unroll
    for (int c = 0; c < 32; ++c) a = fmaf(X[tid*32+c], X[tid*32+c], a);
    xx[tid] = a;
  }
  __syncthreads();
  if (tid < NPT) {
    const int n = tid;
    float xr[32];
    #pragma unroll
    for (int c = 0; c < 32; ++c) xr[c] = X[n*32+c];
    const float xxn = xx[n];
    float bv[KK]; short bi[KK];
    #pragma unroll
    for (int k = 0; k < KK; ++k) { bv[k] = -3.4e38f; bi[k] = 0; }
    for (int m = 0; m < NPT; ++m) {
      const float* Xm = X + m*32;
      float p0=0.f,p1=0.f,p2=0.f,p3=0.f;
      #pragma unroll
      for (int c = 0; c < 32; c += 4) {
        p0 = fmaf(xr[c],   Xm[c],   p0);
        p1 = fmaf(xr[c+1], Xm[c+1], p1);
        p2 = fmaf(xr[c+2], Xm[c+2], p2);
        p3 = fmaf(xr[c+3], Xm[c+3], p3);
      }
      const float inner = (p0+p1)+(p2+p3);
      const float d = 2.0f*inner - xxn - xx[m];
      if (d > bv[KK-1]) {           // strict >: incumbent (earlier m) wins ties
        float cv = d; short ci = (short)m;
        #pragma unroll
        for (int j = 0; j < KK; ++j) {   // ascending bubble: stable insert
          bool sw = cv > bv[j];
          float tv = bv[j]; short ti = bi[j];
          bv[j] = sw ? cv : tv; bi[j] = sw ? ci : ti;
          cv = sw ? tv : cv;    ci = sw ? ti : ci;
        }
      }
    }
    #pragma unroll
    for (int k = 0; k < KK; ++k) idx[n*KK+k] = bi[k];
  }
  __syncthreads();
}

// ---- EdgeConv: P/Q decomposition + (optional) 32x32 conv + max over k ------
__device__ __forceinline__ void econv(const float* __restrict__ Xin,
                                      float* __restrict__ Xout,
                                      float* __restrict__ P,     // 3200
                                      float* __restrict__ E,     // NCH*324 (may alias Xout when Wb==null)
                                      float* __restrict__ Qc,    // NCH*32
                                      float* __restrict__ Wst,   // 2048
                                      const short* __restrict__ idx,
                                      const float* __restrict__ Wa,  // 32x64
                                      const float* __restrict__ Wb,  // 32x32 or null
                                      const float* __restrict__ sa, const float* __restrict__ ta,
                                      const float* __restrict__ sb, const float* __restrict__ tb,
                                      int tid) {
  // stage Wa transposed: Wst[c*32+o] (one-time conflicted write, conflict-free reads)
  for (int i = tid; i < 2048; i += 256) {
    int o = i >> 6, c = i & 63;
    Wst[c*32 + o] = Wa[i];
  }
  __syncthreads();
  // P[j][o] = sum_c Wa[o][c] * Xin[j][c]
  for (int p = tid; p < 3200; p += 256) {
    int j = p >> 5, o = p & 31;
    float a0=0.f, a1=0.f;
    #pragma unroll
    for (int c = 0; c < 32; c += 2) {
      a0 = fmaf(Wst[c*32+o],     Xin[j*32+c],   a0);
      a1 = fmaf(Wst[(c+1)*32+o], Xin[j*32+c+1], a1);
    }
    P[p] = a0 + a1;
  }
  __syncthreads();

  for (int nb = 0; nb < NPT; nb += NCH) {
    const int nc = min(NCH, NPT - nb);
    // Qc[nn][o] = sum_c (Wa[o][32+c]-Wa[o][c]) * Xin[n][c]
    for (int p = tid; p < nc*32; p += 256) {
      int nn = p >> 5, o = p & 31, n = nb + nn;
      float a = 0.f;
      #pragma unroll
      for (int c = 0; c < 32; ++c) {
        float wd = Wst[(32+c)*32+o] - Wst[c*32+o];
        a = fmaf(wd, Xin[n*32+c], a);
      }
      Qc[p] = a;
    }
    __syncthreads();

    if (Wb) {
      // edge features E[nn][k][c] (row stride 324 -> 2-way-max bank aliasing)
      for (int p = tid; p < nc*320; p += 256) {
        int c = p & 31, k = (p >> 5) % KK, nn = p / 320, n = nb + nn;
        int j = (int)idx[n*KK+k];
        float v = P[j*32+c] + Qc[nn*32+c];
        v = fmaf(v, sa[c], ta[c]);
        E[nn*324 + k*32 + c] = leaky(v);
      }
      __syncthreads();
      // 32x32 conv over edges + max over k (activation folded past max)
      for (int p = tid; p < nc*32; p += 256) {
        int o = p / nc, nn = p % nc, n = nb + nn;
        float acc[KK];
        #pragma unroll
        for (int k = 0; k < KK; ++k) acc[k] = 0.f;
        #pragma unroll
        for (int c4 = 0; c4 < 8; ++c4) {
          const float4 w = *(const float4*)&Wb[o*32 + c4*4];  // few lines/wave, L1-hot
          #pragma unroll
          for (int k = 0; k < KK; ++k) {
            const float4 e = *(const float4*)&E[nn*324 + k*32 + c4*4];
            acc[k] = fmaf(w.x, e.x, fmaf(w.y, e.y, fmaf(w.z, e.z, fmaf(w.w, e.w, acc[k]))));
          }
        }
        float m = acc[0];
        #pragma unroll
        for (int k = 1; k < KK; ++k) m = fmaxf(m, acc[k]);
        Xout[n*32 + o] = leaky(fmaf(m, sb[o], tb[o]));
      }
      __syncthreads();
    } else {
      // last edgeconv: no second conv -> x3[n][o] = leaky((Q + max_k P[j])*s+t)
      for (int p = tid; p < nc*32; p += 256) {
        int nn = p >> 5, o = p & 31, n = nb + nn;
        float m = -3.4e38f;
        #pragma unroll
        for (int k = 0; k < KK; ++k) {
          int j = (int)idx[n*KK+k];
          m = fmaxf(m, P[j*32+o]);
        }
        Xout[n*32+o] = leaky(fmaf(m + Qc[nn*32+o], sa[o], ta[o]));
      }
      __syncthreads();
    }
  }
}

__global__ __launch_bounds__(256) void dgcnn(Params pr) {
  const int b = blockIdx.x;
  const int tid = threadIdx.x;

  // ---- LDS region map (63,952 B total) ----
  __shared__ __align__(16) float A [3200];  // x1
  __shared__ __align__(16) float Bx[3200];  // X0, then x2
  __shared__ __align__(16) float Cx[3200];  // obs stage -> E buffer -> x3
  __shared__ __align__(16) float Dx[3200];  // P -> h2c[16][129] + h3c[16][33]
  __shared__ __align__(16) float Ex[320];   // xx / Qc
  __shared__ __align__(16) float Fx[2368];  // weight staging; W6: [Wc|g|red]; W7: [Wc|g(dead)|Rg|W9]
  __shared__ short Gi[NPT*KK];              // knn indices

  // ================= conv0: 30 -> 32 =================
  for (int i = tid; i < 3000; i += 256) Cx[i] = pr.obs[b*3000 + i];
  for (int i = tid; i < 960; i += 256) {       // W0T padded [30][33]
    int o = i / 30, c = i % 30;
    Fx[c*33 + o] = pr.W[0][i];
  }
  __syncthreads();
  for (int p = tid; p < 3200; p += 256) {
    int n = p >> 5, o = p & 31;
    float a0=0.f, a1=0.f;
    #pragma unroll
    for (int c = 0; c < 30; c += 2) {
      a0 = fmaf(Fx[c*33+o],     Cx[n*30+c],   a0);
      a1 = fmaf(Fx[(c+1)*33+o], Cx[n*30+c+1], a1);
    }
    Bx[p] = leaky(fmaf(a0+a1, pr.s[0][o], pr.t[0][o]));
  }
  __syncthreads();

  // ================= edgeconv 1..3 =================
  knn_topk(Bx, Ex, Gi, tid);
  econv(Bx, A,  Dx, Cx, Ex, Fx, Gi, pr.W[1], pr.W[2], pr.s[1], pr.t[1], pr.s[2], pr.t[2], tid);
  knn_topk(A, Ex, Gi, tid);
  econv(A,  Bx, Dx, Cx, Ex, Fx, Gi, pr.W[3], pr.W[4], pr.s[3], pr.t[3], pr.s[4], pr.t[4], tid);
  knn_topk(Bx, Ex, Gi, tid);
  econv(Bx, Cx, Dx, nullptr, Ex, Fx, Gi, pr.W[5], nullptr, pr.s[5], pr.t[5], nullptr, nullptr, tid);

  // ================= W6 (512x96) + global max over n -> g =================
  float* gbuf = Fx + 1600;
  float* red  = Fx + 2112;
  for (int oc = 0; oc < 32; ++oc) {           // 16 outputs per chunk
    for (int i = tid; i < 1536; i += 256) {   // stage W6 chunk [16][100-padded]
      int o = i / 96, c = i % 96;
      Fx[o*100 + c] = pr.W[6][(oc*16+o)*96 + c];
    }
    __syncthreads();
    {
      int grp = tid >> 4, o = tid & 15;
      int n0  = (grp < 4) ? grp*7 : 28 + (grp-4)*6;
      int cnt = (grp < 4) ? 7 : 6;
      float acc[7];
      #pragma unroll
      for (int i = 0; i < 7; ++i) acc[i] = 0.f;
      #pragma unroll
      for (int c4 = 0; c4 < 24; ++c4) {
        const float4 w = *(const float4*)&Fx[o*100 + c4*4];
        int cc = c4*4;
        const float* src = (cc < 32) ? (A + cc) : (cc < 64 ? (Bx + cc - 32) : (Cx + cc - 64));
        for (int i = 0; i < cnt; ++i) {
          const float4 xv = *(const float4*)&src[(n0+i)*32];   // broadcast within wave
          acc[i] = fmaf(w.x, xv.x, fmaf(w.y, xv.y, fmaf(w.z, xv.z, fmaf(w.w, xv.w, acc[i]))));
        }
      }
      float m = acc[0];
      for (int i = 1; i < cnt; ++i) m = fmaxf(m, acc[i]);
      red[grp*16 + o] = m;
    }
    __syncthreads();
    if (tid < 16) {
      float mm = red[tid];
      #pragma unroll
      for (int g2 = 1; g2 < 16; ++g2) mm = fmaxf(mm, red[g2*16 + tid]);
      int og = oc*16 + tid;
      gbuf[og] = leaky(fmaf(mm, pr.s[6][og], pr.t[6][og]));
    }
    __syncthreads();
  }

  // ================= Rg[o] = W7[o, :512] . g  (once per block) =================
  {
    int wave = tid >> 6, lane = tid & 63;
    for (int o = wave; o < 128; o += 4) {
      float a = 0.f;
      #pragma unroll
      for (int cb = 0; cb < 8; ++cb) {
        int c = cb*64 + lane;
        a = fmaf(pr.W[7][o*608 + c], gbuf[c], a);
      }
      #pragma unroll
      for (int off = 32; off >= 1; off >>= 1) a += __shfl_xor(a, off, 64);
      if (lane == 0) Fx[2112 + o] = a;
    }
    if (tid < 32) Fx[2240 + tid] = pr.W[9][tid];
  }
  __syncthreads();

  // ================= W7 (96-ch part) -> W8 -> W9, n-chunks of 16 =================
  float* h2c = Dx;               // [16][129]
  float* h3c = Dx + 2064;        // [16][33]
  const float* Rg  = Fx + 2112;
  const float* sW9 = Fx + 2240;
  for (int nb = 0; nb < NPT; nb += 16) {
    const int nc = min(16, NPT - nb);
    for (int ocb = 0; ocb < 8; ++ocb) {
      for (int i = tid; i < 1536; i += 256) {   // stage W7 per-point part [16][100-padded]
        int o = i / 96, c = i % 96;
        Fx[o*100 + c] = pr.W[7][(ocb*16+o)*608 + 512 + c];
      }
      __syncthreads();
      {
        int o = tid & 15, nn = tid >> 4;
        if (nn < nc) {
          float a = 0.f;
          #pragma unroll
          for (int c4 = 0; c4 < 24; ++c4) {
            const float4 w = *(const float4*)&Fx[o*100 + c4*4];
            int cc = c4*4;
            const float* src = (cc < 32) ? (A + cc) : (cc < 64 ? (Bx + cc - 32) : (Cx + cc - 64));
            const float4 xv = *(const float4*)&src[(nb+nn)*32];
            a = fmaf(w.x, xv.x, fmaf(w.y, xv.y, fmaf(w.z, xv.z, fmaf(w.w, xv.w, a))));
          }
          int og = ocb*16 + o;
          h2c[nn*129 + og] = leaky(fmaf(Rg[og] + a, pr.s[7][og], pr.t[7][og]));
        }
      }
      __syncthreads();
    }
    // W8 (32x128) + leaky -> h3c
    for (int p = tid; p < 32*nc; p += 256) {
      int o8 = p / nc, nn = p % nc;
      const float* w8r = pr.W[8] + o8*128;     // 2-4 lines/wave, L1-hot
      const float* hr  = h2c + nn*129;         // stride 129 -> conflict-free
      float a0=0.f, a1=0.f;
      #pragma unroll
      for (int c = 0; c < 128; c += 2) {
        a0 = fmaf(w8r[c],   hr[c],   a0);
        a1 = fmaf(w8r[c+1], hr[c+1], a1);
      }
      h3c[nn*33 + o8] = leaky(fmaf(a0+a1, pr.s[8][o8], pr.t[8][o8]));
    }
    __syncthreads();
    // W9 (1x32) -> output
    if (tid < nc) {
      float a = 0.f;
      #pragma unroll
      for (int o8 = 0; o8 < 32; ++o8) a = fmaf(sW9[o8], h3c[tid*33 + o8], a);
      pr.out[b*NPT + nb + tid] = a;
    }
    __syncthreads();
  }
}

extern "C" void kernel_launch(void* const* d_in, const int* in_sizes, int n_in,
                              void* d_out, int out_size, void* d_ws, size_t ws_size,
                              hipStream_t stream) {
  Params pr;
  pr.obs = (const float*)d_in[0];
  for (int i = 0; i < 10; ++i) pr.W[i] = (const float*)d_in[1 + i];
  for (int i = 0; i < 9; ++i) {
    pr.s[i] = (const float*)d_in[11 + 2*i];
    pr.t[i] = (const float*)d_in[12 + 2*i];
  }
  pr.out = (float*)d_out;
  const int B = in_sizes[0] / 3000;   // 1024
  dgcnn<<<B, 256, 0, stream>>>(pr);
}